// Round 1
// baseline (371.460 us; speedup 1.0000x reference)
//
#include <hip/hip_runtime.h>
#include <hip/hip_bf16.h>

#define T_DIM 2048
#define B_DIM 8
#define D_DIM 1024
#define H_DIM 1024
#define M_DIM (T_DIM * B_DIM)   // 16384 rows
#define NCH (B_DIM * H_DIM)     // 8192 channels
#define CHUNK 128
#define NCHUNK (T_DIM / CHUNK)  // 16

typedef __bf16 bf16x8 __attribute__((ext_vector_type(8)));
typedef unsigned short us8 __attribute__((ext_vector_type(8)));
typedef float f32x4 __attribute__((ext_vector_type(4)));

__device__ __forceinline__ unsigned short f2bf(float f) {
    unsigned u = __float_as_uint(f);
    u += 0x7fffu + ((u >> 16) & 1u);   // round-to-nearest-even
    return (unsigned short)(u >> 16);
}
__device__ __forceinline__ float bflo(unsigned u) { return __uint_as_float(u << 16); }
__device__ __forceinline__ float bfhi(unsigned u) { return __uint_as_float(u & 0xffff0000u); }

// Dual GEMM: z1 = x@Wd^T + bd -> decay = sigmoid(-z1);  bx = x@Wb^T + bb
// Writes packed {decay(lo), bx(hi)} bf16x2 per element into db[M][H].
__global__ __launch_bounds__(256, 2) void proj_kernel(
    const float* __restrict__ x, const float* __restrict__ Wd,
    const float* __restrict__ bd, const float* __restrict__ Wb,
    const float* __restrict__ bb, unsigned int* __restrict__ db)
{
    // LDS: [kchunk][row][8 bf16] 16B cells, XOR-swizzled by kc
    __shared__ us8 ldsA[8][128];
    __shared__ us8 ldsB[2][8][128];

    const int tid  = threadIdx.x;
    const int lane = tid & 63;
    const int wid  = tid >> 6;
    const int wm = wid >> 1, wn = wid & 1;       // 2x2 waves, 64x64 each
    const int bRow = blockIdx.x * 128;           // M tile
    const int bCol = blockIdx.y * 128;           // H tile

    f32x4 accD[4][4], accB[4][4];
    #pragma unroll
    for (int i = 0; i < 4; ++i)
        #pragma unroll
        for (int j = 0; j < 4; ++j) { accD[i][j] = (f32x4)0.0f; accB[i][j] = (f32x4)0.0f; }

    for (int kt = 0; kt < D_DIM; kt += 64) {
        // ---- stage A tile (128 x 64), fp32 -> bf16 on the fly ----
        #pragma unroll
        for (int p = 0; p < 4; ++p) {
            int ci = tid + p * 256;              // 1024 cells of 8 elems
            int kc = ci & 7, row = ci >> 3;
            const float* src = x + (size_t)(bRow + row) * D_DIM + kt + kc * 8;
            float4 f0 = *(const float4*)src;
            float4 f1 = *(const float4*)(src + 4);
            us8 u;
            u[0]=f2bf(f0.x); u[1]=f2bf(f0.y); u[2]=f2bf(f0.z); u[3]=f2bf(f0.w);
            u[4]=f2bf(f1.x); u[5]=f2bf(f1.y); u[6]=f2bf(f1.z); u[7]=f2bf(f1.w);
            ldsA[kc][row ^ kc] = u;
        }
        // ---- stage both B tiles (W_delta, W_B) ----
        #pragma unroll
        for (int w = 0; w < 2; ++w) {
            const float* W = w ? Wb : Wd;
            #pragma unroll
            for (int p = 0; p < 4; ++p) {
                int ci = tid + p * 256;
                int kc = ci & 7, col = ci >> 3;
                const float* src = W + (size_t)(bCol + col) * D_DIM + kt + kc * 8;
                float4 f0 = *(const float4*)src;
                float4 f1 = *(const float4*)(src + 4);
                us8 u;
                u[0]=f2bf(f0.x); u[1]=f2bf(f0.y); u[2]=f2bf(f0.z); u[3]=f2bf(f0.w);
                u[4]=f2bf(f1.x); u[5]=f2bf(f1.y); u[6]=f2bf(f1.z); u[7]=f2bf(f1.w);
                ldsB[w][kc][col ^ kc] = u;
            }
        }
        __syncthreads();

        #pragma unroll
        for (int ks = 0; ks < 2; ++ks) {
            const int kc = ks * 4 + (lane >> 4);
            bf16x8 aF[4];
            #pragma unroll
            for (int mt = 0; mt < 4; ++mt)
                aF[mt] = __builtin_bit_cast(bf16x8, ldsA[kc][(wm*64 + mt*16 + (lane&15)) ^ kc]);
            #pragma unroll
            for (int nt = 0; nt < 4; ++nt) {
                int cIdx = (wn*64 + nt*16 + (lane&15)) ^ kc;
                bf16x8 b0 = __builtin_bit_cast(bf16x8, ldsB[0][kc][cIdx]);
                bf16x8 b1 = __builtin_bit_cast(bf16x8, ldsB[1][kc][cIdx]);
                #pragma unroll
                for (int mt = 0; mt < 4; ++mt) {
                    accD[mt][nt] = __builtin_amdgcn_mfma_f32_16x16x32_bf16(aF[mt], b0, accD[mt][nt], 0, 0, 0);
                    accB[mt][nt] = __builtin_amdgcn_mfma_f32_16x16x32_bf16(aF[mt], b1, accB[mt][nt], 0, 0, 0);
                }
            }
        }
        __syncthreads();
    }

    // ---- epilogue: decay = sigmoid(-(z+bd)); bx = y+bb; pack bf16x2 ----
    #pragma unroll
    for (int nt = 0; nt < 4; ++nt) {
        int c = bCol + wn*64 + nt*16 + (lane & 15);
        float bdv = bd[c], bbv = bb[c];
        #pragma unroll
        for (int mt = 0; mt < 4; ++mt) {
            int r0 = bRow + wm*64 + mt*16 + ((lane >> 4) << 2);
            #pragma unroll
            for (int reg = 0; reg < 4; ++reg) {
                float z  = accD[mt][nt][reg] + bdv;
                float dk = 1.0f / (1.0f + __expf(z));   // exp(-softplus(z)) exactly
                float bx = accB[mt][nt][reg] + bbv;
                db[(size_t)(r0 + reg) * H_DIM + c] =
                    (unsigned)f2bf(dk) | ((unsigned)f2bf(bx) << 16);
            }
        }
    }
}

// Phase 1 of chunked scan: per (chunk, channel) compute affine composite (A, Bc)
__global__ void scan_reduce(const unsigned int* __restrict__ db,
                            float* __restrict__ cA, float* __restrict__ cB)
{
    int c = blockIdx.y * 256 + threadIdx.x;
    int i = blockIdx.x;
    const unsigned int* p = db + (size_t)i * CHUNK * NCH + c;
    float A = 1.0f, Bc = 0.0f;
    for (int t = 0; t < CHUNK; ++t) {
        unsigned u = p[(size_t)t * NCH];
        float a  = bflo(u);
        float bx = bfhi(u);
        A  *= a;
        Bc  = a * Bc + (1.0f - a) * bx;
    }
    cA[i * NCH + c] = A;
    cB[i * NCH + c] = Bc;
}

// Phase 2: sequential scan over the 16 chunk composites -> h at each chunk start
__global__ void scan_chunks(const float* __restrict__ cA, const float* __restrict__ cB,
                            const float* __restrict__ h0, float* __restrict__ hstart)
{
    int c = blockIdx.x * 256 + threadIdx.x;
    float h = h0[c];
    #pragma unroll
    for (int i = 0; i < NCHUNK; ++i) {
        hstart[i * NCH + c] = h;
        h = cA[i * NCH + c] * h + cB[i * NCH + c];
    }
}

// Phase 3: replay each chunk with the correct initial h, write outputs (fp32)
__global__ void scan_apply(const unsigned int* __restrict__ db,
                           const float* __restrict__ hstart, float* __restrict__ out)
{
    int c = blockIdx.y * 256 + threadIdx.x;
    int i = blockIdx.x;
    float h = hstart[i * NCH + c];
    const unsigned int* p = db + (size_t)i * CHUNK * NCH + c;
    float* o = out + (size_t)i * CHUNK * NCH + c;
    for (int t = 0; t < CHUNK; ++t) {
        unsigned u = p[(size_t)t * NCH];
        float a  = bflo(u);
        float bx = bfhi(u);
        h = a * h + (1.0f - a) * bx;
        o[(size_t)t * NCH] = h;
    }
}

extern "C" void kernel_launch(void* const* d_in, const int* in_sizes, int n_in,
                              void* d_out, int out_size, void* d_ws, size_t ws_size,
                              hipStream_t stream) {
    const float* x  = (const float*)d_in[0];
    const float* h0 = (const float*)d_in[1];
    const float* Wd = (const float*)d_in[2];
    const float* bd = (const float*)d_in[3];
    const float* Wb = (const float*)d_in[4];
    const float* bb = (const float*)d_in[5];
    float* out = (float*)d_out;

    char* ws = (char*)d_ws;
    unsigned int* db = (unsigned int*)ws;                       // M*H uint = 64 MiB
    float* cA     = (float*)(ws + (size_t)M_DIM * H_DIM * 4);   // 16*8192 f32
    float* cB     = cA + NCHUNK * NCH;
    float* hstart = cB + NCHUNK * NCH;

    dim3 gProj(M_DIM / 128, H_DIM / 128);   // 128 x 8 = 1024 blocks
    proj_kernel<<<gProj, 256, 0, stream>>>(x, Wd, bd, Wb, bb, db);

    scan_reduce<<<dim3(NCHUNK, NCH / 256), 256, 0, stream>>>(db, cA, cB);
    scan_chunks<<<NCH / 256, 256, 0, stream>>>(cA, cB, h0, hstart);
    scan_apply<<<dim3(NCHUNK, NCH / 256), 256, 0, stream>>>(db, hstart, out);
}

// Round 7
// 274.537 us; speedup vs baseline: 1.3530x; 1.3530x over previous
//
#include <hip/hip_runtime.h>
#include <hip/hip_bf16.h>

#define T_DIM 2048
#define B_DIM 8
#define D_DIM 1024
#define H_DIM 1024
#define M_DIM (T_DIM * B_DIM)   // 16384 rows
#define NCH (B_DIM * H_DIM)     // 8192 channels
#define CHUNK 64
#define NCHUNK (T_DIM / CHUNK)  // 32
#define NCH2 (NCH / 2)          // 4096 channel-pairs

typedef __bf16 bf16x8 __attribute__((ext_vector_type(8)));
typedef unsigned short us8 __attribute__((ext_vector_type(8)));
typedef float f32x4 __attribute__((ext_vector_type(4)));

__device__ __forceinline__ unsigned short f2bf(float f) {
    unsigned u = __float_as_uint(f);
    u += 0x7fffu + ((u >> 16) & 1u);   // round-to-nearest-even
    return (unsigned short)(u >> 16);
}
__device__ __forceinline__ float bflo(unsigned u) { return __uint_as_float(u << 16); }
__device__ __forceinline__ float bfhi(unsigned u) { return __uint_as_float(u & 0xffff0000u); }

// ---- one-shot fp32 -> bf16 conversion of x, W_delta, W_B ----
#define XCELLS  (M_DIM * D_DIM / 8)          // 2097152
#define WCELLS  (H_DIM * D_DIM / 8)          // 131072
__global__ __launch_bounds__(256) void convert_kernel(
    const float* __restrict__ x, const float* __restrict__ Wd,
    const float* __restrict__ Wb, unsigned short* __restrict__ xb,
    unsigned short* __restrict__ wdb, unsigned short* __restrict__ wbb)
{
    size_t cell = (size_t)blockIdx.x * 256 + threadIdx.x;
    const float* src; unsigned short* dst;
    if (cell < XCELLS)               { src = x  + cell * 8;                    dst = xb  + cell * 8; }
    else if (cell < XCELLS + WCELLS) { size_t c = cell - XCELLS;  src = Wd + c * 8; dst = wdb + c * 8; }
    else                             { size_t c = cell - XCELLS - WCELLS; src = Wb + c * 8; dst = wbb + c * 8; }
    float4 f0 = *(const float4*)src;
    float4 f1 = *(const float4*)(src + 4);
    us8 u;
    u[0]=f2bf(f0.x); u[1]=f2bf(f0.y); u[2]=f2bf(f0.z); u[3]=f2bf(f0.w);
    u[4]=f2bf(f1.x); u[5]=f2bf(f1.y); u[6]=f2bf(f1.z); u[7]=f2bf(f1.w);
    *(us8*)dst = u;
}

// ---- dual GEMM, m97 structure: global_load_lds(16B) staging, 128x128 tile, BK=64
// LDS cell layout: tile[128 rows][8 slots of 16B], cell = row*8 + (kc ^ (row&7)).
// Staging keeps LDS linear (HW requirement) and pre-swizzles the GLOBAL source.
__global__ __launch_bounds__(256) void proj_kernel(
    const unsigned short* __restrict__ xb, const unsigned short* __restrict__ wdb,
    const unsigned short* __restrict__ wbb, const float* __restrict__ bd,
    const float* __restrict__ bb, unsigned int* __restrict__ db)
{
    __shared__ us8 sA[1024];
    __shared__ us8 sB0[1024];
    __shared__ us8 sB1[1024];

    const int tid  = threadIdx.x;
    const int lane = tid & 63;
    const int wid  = tid >> 6;
    const int wm = wid >> 1, wn = wid & 1;       // 2x2 waves, 64x64 out each
    const int bRow = blockIdx.x * 128;
    const int bCol = blockIdx.y * 128;

    f32x4 accD[4][4], accB[4][4];
    #pragma unroll
    for (int i = 0; i < 4; ++i)
        #pragma unroll
        for (int j = 0; j < 4; ++j) { accD[i][j] = (f32x4)0.0f; accB[i][j] = (f32x4)0.0f; }

    const unsigned short* aBase  = xb  + (size_t)bRow * D_DIM;
    const unsigned short* b0Base = wdb + (size_t)bCol * D_DIM;
    const unsigned short* b1Base = wbb + (size_t)bCol * D_DIM;

    for (int kt = 0; kt < D_DIM; kt += 64) {
        #pragma unroll
        for (int p = 0; p < 4; ++p) {
            int ci  = p * 256 + tid;             // linear cell index (wave-contiguous)
            int row = ci >> 3;
            int kc  = (ci & 7) ^ (row & 7);      // pre-swizzled source slot
            size_t goff = (size_t)row * D_DIM + kt + kc * 8;
            __builtin_amdgcn_global_load_lds(
                (const __attribute__((address_space(1))) unsigned int*)(aBase + goff),
                (__attribute__((address_space(3))) unsigned int*)(sA + p * 256 + wid * 64),
                16, 0, 0);
            __builtin_amdgcn_global_load_lds(
                (const __attribute__((address_space(1))) unsigned int*)(b0Base + goff),
                (__attribute__((address_space(3))) unsigned int*)(sB0 + p * 256 + wid * 64),
                16, 0, 0);
            __builtin_amdgcn_global_load_lds(
                (const __attribute__((address_space(1))) unsigned int*)(b1Base + goff),
                (__attribute__((address_space(3))) unsigned int*)(sB1 + p * 256 + wid * 64),
                16, 0, 0);
        }
        __syncthreads();

        #pragma unroll
        for (int ks = 0; ks < 2; ++ks) {
            const int kc = ks * 4 + (lane >> 4);
            bf16x8 aF[4], b0F[4], b1F[4];
            #pragma unroll
            for (int q = 0; q < 4; ++q) {
                int r = wm * 64 + q * 16 + (lane & 15);
                aF[q]  = __builtin_bit_cast(bf16x8, sA [r * 8 + (kc ^ (r & 7))]);
                int c = wn * 64 + q * 16 + (lane & 15);
                b0F[q] = __builtin_bit_cast(bf16x8, sB0[c * 8 + (kc ^ (c & 7))]);
                b1F[q] = __builtin_bit_cast(bf16x8, sB1[c * 8 + (kc ^ (c & 7))]);
            }
            #pragma unroll
            for (int nt = 0; nt < 4; ++nt)
                #pragma unroll
                for (int mt = 0; mt < 4; ++mt) {
                    accD[mt][nt] = __builtin_amdgcn_mfma_f32_16x16x32_bf16(aF[mt], b0F[nt], accD[mt][nt], 0, 0, 0);
                    accB[mt][nt] = __builtin_amdgcn_mfma_f32_16x16x32_bf16(aF[mt], b1F[nt], accB[mt][nt], 0, 0, 0);
                }
        }
        __syncthreads();
    }

    // epilogue: decay = sigmoid(-(z+bd)) = exp(-softplus(z+bd)); bx = y+bb
    #pragma unroll
    for (int nt = 0; nt < 4; ++nt) {
        int c = bCol + wn * 64 + nt * 16 + (lane & 15);
        float bdv = bd[c], bbv = bb[c];
        #pragma unroll
        for (int mt = 0; mt < 4; ++mt) {
            int r0 = bRow + wm * 64 + mt * 16 + ((lane >> 4) << 2);
            #pragma unroll
            for (int reg = 0; reg < 4; ++reg) {
                float z  = accD[mt][nt][reg] + bdv;
                float dk = 1.0f / (1.0f + __expf(z));
                float bx = accB[mt][nt][reg] + bbv;
                db[(size_t)(r0 + reg) * H_DIM + c] =
                    (unsigned)f2bf(dk) | ((unsigned)f2bf(bx) << 16);
            }
        }
    }
}

// ---- chunked scan, uint2/float2 vectorized (2 channels/lane) ----
__global__ __launch_bounds__(256) void scan_reduce(
    const uint2* __restrict__ db2, float2* __restrict__ cA, float2* __restrict__ cB)
{
    int c2 = blockIdx.y * 256 + threadIdx.x;
    int i  = blockIdx.x;
    const uint2* p = db2 + (size_t)i * CHUNK * NCH2 + c2;
    float A0 = 1.0f, B0 = 0.0f, A1 = 1.0f, B1 = 0.0f;
    for (int t = 0; t < CHUNK; ++t) {
        uint2 u = p[(size_t)t * NCH2];
        float a0 = bflo(u.x), bx0 = bfhi(u.x);
        float a1 = bflo(u.y), bx1 = bfhi(u.y);
        A0 *= a0; B0 = a0 * B0 + (1.0f - a0) * bx0;
        A1 *= a1; B1 = a1 * B1 + (1.0f - a1) * bx1;
    }
    cA[i * NCH2 + c2] = make_float2(A0, A1);
    cB[i * NCH2 + c2] = make_float2(B0, B1);
}

__global__ __launch_bounds__(256) void scan_chunks(
    const float2* __restrict__ cA, const float2* __restrict__ cB,
    const float2* __restrict__ h0, float2* __restrict__ hstart)
{
    int c2 = blockIdx.x * 256 + threadIdx.x;
    float2 h = h0[c2];
    #pragma unroll
    for (int i = 0; i < NCHUNK; ++i) {
        hstart[i * NCH2 + c2] = h;
        float2 a = cA[i * NCH2 + c2];
        float2 b = cB[i * NCH2 + c2];
        h.x = a.x * h.x + b.x;
        h.y = a.y * h.y + b.y;
    }
}

__global__ __launch_bounds__(256) void scan_apply(
    const uint2* __restrict__ db2, const float2* __restrict__ hstart,
    float2* __restrict__ out2)
{
    int c2 = blockIdx.y * 256 + threadIdx.x;
    int i  = blockIdx.x;
    float2 h = hstart[i * NCH2 + c2];
    const uint2* p = db2 + (size_t)i * CHUNK * NCH2 + c2;
    float2*      o = out2 + (size_t)i * CHUNK * NCH2 + c2;
    for (int t = 0; t < CHUNK; ++t) {
        uint2 u = p[(size_t)t * NCH2];
        float a0 = bflo(u.x), bx0 = bfhi(u.x);
        float a1 = bflo(u.y), bx1 = bfhi(u.y);
        h.x = a0 * h.x + (1.0f - a0) * bx0;
        h.y = a1 * h.y + (1.0f - a1) * bx1;
        o[(size_t)t * NCH2] = h;
    }
}

extern "C" void kernel_launch(void* const* d_in, const int* in_sizes, int n_in,
                              void* d_out, int out_size, void* d_ws, size_t ws_size,
                              hipStream_t stream) {
    const float* x  = (const float*)d_in[0];
    const float* h0 = (const float*)d_in[1];
    const float* Wd = (const float*)d_in[2];
    const float* bd = (const float*)d_in[3];
    const float* Wb = (const float*)d_in[4];
    const float* bb = (const float*)d_in[5];
    float* out = (float*)d_out;

    // ws: only what scan_apply READS while out is being written (no aliasing
    // with d_out allowed for those): db (64 MiB) + hstart (1 MiB) = 65 MiB.
    char* ws = (char*)d_ws;
    unsigned int* db = (unsigned int*)ws;                           // 64 MiB
    float* hstart = (float*)(ws + (size_t)M_DIM * H_DIM * 4);       // 1 MiB

    // d_out doubles as scratch until scan_apply overwrites it (64 MiB):
    //   xb 32 MiB | wdb 2 MiB | wbb 2 MiB | cA 1 MiB | cB 1 MiB   (= 38 MiB)
    char* ob = (char*)d_out;
    unsigned short* xb  = (unsigned short*)ob;
    unsigned short* wdb = (unsigned short*)(ob + ((size_t)32 << 20));
    unsigned short* wbb = (unsigned short*)(ob + ((size_t)34 << 20));
    float* cA = (float*)(ob + ((size_t)36 << 20));
    float* cB = (float*)(ob + ((size_t)37 << 20));

    convert_kernel<<<(XCELLS + 2 * WCELLS) / 256, 256, 0, stream>>>(x, Wd, Wb, xb, wdb, wbb);

    dim3 gProj(M_DIM / 128, H_DIM / 128);   // 128 x 8 = 1024 blocks
    proj_kernel<<<gProj, 256, 0, stream>>>(xb, wdb, wbb, bd, bb, db);

    scan_reduce<<<dim3(NCHUNK, NCH2 / 256), 256, 0, stream>>>((const uint2*)db, (float2*)cA, (float2*)cB);
    scan_chunks<<<NCH2 / 256, 256, 0, stream>>>((const float2*)cA, (const float2*)cB, (const float2*)h0, (float2*)hstart);
    scan_apply<<<dim3(NCHUNK, NCH2 / 256), 256, 0, stream>>>((const uint2*)db, (const float2*)hstart, (float2*)out);
}

// Round 9
// 241.813 us; speedup vs baseline: 1.5361x; 1.1353x over previous
//
#include <hip/hip_runtime.h>
#include <hip/hip_bf16.h>

#define T_DIM 2048
#define B_DIM 8
#define D_DIM 1024
#define H_DIM 1024
#define M_DIM (T_DIM * B_DIM)   // 16384 rows
#define NCH (B_DIM * H_DIM)     // 8192 channels
#define CHUNK 64
#define NCHUNK (T_DIM / CHUNK)  // 32
#define NCH2 (NCH / 2)          // 4096 channel-pairs

typedef __bf16 bf16x8 __attribute__((ext_vector_type(8)));
typedef unsigned short us8 __attribute__((ext_vector_type(8)));
typedef float f32x4 __attribute__((ext_vector_type(4)));

__device__ __forceinline__ unsigned short f2bf(float f) {
    unsigned u = __float_as_uint(f);
    u += 0x7fffu + ((u >> 16) & 1u);   // round-to-nearest-even
    return (unsigned short)(u >> 16);
}
__device__ __forceinline__ float bflo(unsigned u) { return __uint_as_float(u << 16); }
__device__ __forceinline__ float bfhi(unsigned u) { return __uint_as_float(u & 0xffff0000u); }

// ---- one-shot fp32 -> bf16 conversion of x, W_delta, W_B ----
#define XCELLS  (M_DIM * D_DIM / 8)          // 2097152
#define WCELLS  (H_DIM * D_DIM / 8)          // 131072
__global__ __launch_bounds__(256) void convert_kernel(
    const float* __restrict__ x, const float* __restrict__ Wd,
    const float* __restrict__ Wb, unsigned short* __restrict__ xb,
    unsigned short* __restrict__ wdb, unsigned short* __restrict__ wbb)
{
    size_t cell = (size_t)blockIdx.x * 256 + threadIdx.x;
    const float* src; unsigned short* dst;
    if (cell < XCELLS)               { src = x  + cell * 8;                    dst = xb  + cell * 8; }
    else if (cell < XCELLS + WCELLS) { size_t c = cell - XCELLS;  src = Wd + c * 8; dst = wdb + c * 8; }
    else                             { size_t c = cell - XCELLS - WCELLS; src = Wb + c * 8; dst = wbb + c * 8; }
    float4 f0 = *(const float4*)src;
    float4 f1 = *(const float4*)(src + 4);
    us8 u;
    u[0]=f2bf(f0.x); u[1]=f2bf(f0.y); u[2]=f2bf(f0.z); u[3]=f2bf(f0.w);
    u[4]=f2bf(f1.x); u[5]=f2bf(f1.y); u[6]=f2bf(f1.z); u[7]=f2bf(f1.w);
    *(us8*)dst = u;
}

// ---- dual GEMM, 8-wave 2x4 grid (64x32 per wave per GEMM), 2-phase LDS dbuf.
// LDS per buffer: 3 tiles (A|B0|B1) x 1024 cells of 16B; within-tile layout
// cell = row*8 + (kc ^ (row&7)) -- linear dest for global_load_lds, swizzle
// applied on the pre-swizzled GLOBAL source and on the ds_read address.
__global__ __launch_bounds__(512, 2) void proj_kernel(
    const unsigned short* __restrict__ xb, const unsigned short* __restrict__ wdb,
    const unsigned short* __restrict__ wbb, const float* __restrict__ bd,
    const float* __restrict__ bb, unsigned int* __restrict__ db)
{
    __shared__ us8 lds[2][3072];                 // 2 x 48 KiB

    const int tid  = threadIdx.x;
    const int lane = tid & 63;
    const int wid  = tid >> 6;                   // 0..7
    const int wm = wid >> 2, wn = wid & 3;       // 2x4 waves, 64x32 out each
    const int bRow = blockIdx.x * 128;
    const int bCol = blockIdx.y * 128;

    f32x4 accD[4][2], accB[4][2];
    #pragma unroll
    for (int i = 0; i < 4; ++i)
        #pragma unroll
        for (int j = 0; j < 2; ++j) { accD[i][j] = (f32x4)0.0f; accB[i][j] = (f32x4)0.0f; }

    const unsigned short* aBase  = xb  + (size_t)bRow * D_DIM;
    const unsigned short* b0Base = wdb + (size_t)bCol * D_DIM;
    const unsigned short* b1Base = wbb + (size_t)bCol * D_DIM;

    auto stage = [&](int buf, int kt) {
        #pragma unroll
        for (int p = 0; p < 6; ++p) {            // 6 cells/thread: p<2 A, p<4 B0, else B1
            const unsigned short* base = (p < 2) ? aBase : (p < 4 ? b0Base : b1Base);
            int woff = (p & 1) * 512 + wid * 64; // wave-uniform offset within tile
            int w    = woff + lane;              // cell index within tile
            int row  = w >> 3;
            int kc   = (w & 7) ^ (row & 7);      // pre-swizzled source slot
            __builtin_amdgcn_global_load_lds(
                (const __attribute__((address_space(1))) unsigned int*)
                    (base + (size_t)row * D_DIM + kt + kc * 8),
                (__attribute__((address_space(3))) unsigned int*)
                    (&lds[buf][(p >> 1) * 1024 + woff]),
                16, 0, 0);
        }
    };

    auto compute = [&](int buf) {
        #pragma unroll
        for (int ks = 0; ks < 2; ++ks) {
            const int kc = ks * 4 + (lane >> 4);
            const int sl = kc ^ (lane & 7);      // swizzled 16B slot
            bf16x8 aF[4], b0F[2], b1F[2];
            #pragma unroll
            for (int mt = 0; mt < 4; ++mt) {
                int r = wm * 64 + mt * 16 + (lane & 15);
                aF[mt] = __builtin_bit_cast(bf16x8, lds[buf][r * 8 + sl]);
            }
            #pragma unroll
            for (int nt = 0; nt < 2; ++nt) {
                int c = wn * 32 + nt * 16 + (lane & 15);
                b0F[nt] = __builtin_bit_cast(bf16x8, lds[buf][1024 + c * 8 + sl]);
                b1F[nt] = __builtin_bit_cast(bf16x8, lds[buf][2048 + c * 8 + sl]);
            }
            #pragma unroll
            for (int nt = 0; nt < 2; ++nt)
                #pragma unroll
                for (int mt = 0; mt < 4; ++mt) {
                    accD[mt][nt] = __builtin_amdgcn_mfma_f32_16x16x32_bf16(aF[mt], b0F[nt], accD[mt][nt], 0, 0, 0);
                    accB[mt][nt] = __builtin_amdgcn_mfma_f32_16x16x32_bf16(aF[mt], b1F[nt], accB[mt][nt], 0, 0, 0);
                }
        }
    };

    stage(0, 0);
    __syncthreads();
    for (int t = 0; t < 15; ++t) {
        stage((t + 1) & 1, (t + 1) * 64);        // prefetch next K-tile (other buffer)
        compute(t & 1);                          // MFMA on current buffer
        __syncthreads();                         // one barrier per K-step (drains vm+lgkm)
    }
    compute(1);

    // epilogue: decay = sigmoid(-(z+bd)) = exp(-softplus(z+bd)); bx = y+bb
    #pragma unroll
    for (int nt = 0; nt < 2; ++nt) {
        int c = bCol + wn * 32 + nt * 16 + (lane & 15);
        float bdv = bd[c], bbv = bb[c];
        #pragma unroll
        for (int mt = 0; mt < 4; ++mt) {
            int r0 = bRow + wm * 64 + mt * 16 + ((lane >> 4) << 2);
            #pragma unroll
            for (int reg = 0; reg < 4; ++reg) {
                float z  = accD[mt][nt][reg] + bdv;
                float dk = 1.0f / (1.0f + __expf(z));
                float bx = accB[mt][nt][reg] + bbv;
                db[(size_t)(r0 + reg) * H_DIM + c] =
                    (unsigned)f2bf(dk) | ((unsigned)f2bf(bx) << 16);
            }
        }
    }
}

// ---- chunked scan, uint2/float2 vectorized (2 channels/lane) ----
__global__ __launch_bounds__(256) void scan_reduce(
    const uint2* __restrict__ db2, float2* __restrict__ cA, float2* __restrict__ cB)
{
    int c2 = blockIdx.y * 256 + threadIdx.x;
    int i  = blockIdx.x;
    const uint2* p = db2 + (size_t)i * CHUNK * NCH2 + c2;
    float A0 = 1.0f, B0 = 0.0f, A1 = 1.0f, B1 = 0.0f;
    for (int t = 0; t < CHUNK; ++t) {
        uint2 u = p[(size_t)t * NCH2];
        float a0 = bflo(u.x), bx0 = bfhi(u.x);
        float a1 = bflo(u.y), bx1 = bfhi(u.y);
        A0 *= a0; B0 = a0 * B0 + (1.0f - a0) * bx0;
        A1 *= a1; B1 = a1 * B1 + (1.0f - a1) * bx1;
    }
    cA[i * NCH2 + c2] = make_float2(A0, A1);
    cB[i * NCH2 + c2] = make_float2(B0, B1);
}

__global__ __launch_bounds__(256) void scan_chunks(
    const float2* __restrict__ cA, const float2* __restrict__ cB,
    const float2* __restrict__ h0, float2* __restrict__ hstart)
{
    int c2 = blockIdx.x * 256 + threadIdx.x;
    float2 h = h0[c2];
    #pragma unroll
    for (int i = 0; i < NCHUNK; ++i) {
        hstart[i * NCH2 + c2] = h;
        float2 a = cA[i * NCH2 + c2];
        float2 b = cB[i * NCH2 + c2];
        h.x = a.x * h.x + b.x;
        h.y = a.y * h.y + b.y;
    }
}

__global__ __launch_bounds__(256) void scan_apply(
    const uint2* __restrict__ db2, const float2* __restrict__ hstart,
    float2* __restrict__ out2)
{
    int c2 = blockIdx.y * 256 + threadIdx.x;
    int i  = blockIdx.x;
    float2 h = hstart[i * NCH2 + c2];
    const uint2* p = db2 + (size_t)i * CHUNK * NCH2 + c2;
    float2*      o = out2 + (size_t)i * CHUNK * NCH2 + c2;
    for (int t = 0; t < CHUNK; ++t) {
        uint2 u = p[(size_t)t * NCH2];
        float a0 = bflo(u.x), bx0 = bfhi(u.x);
        float a1 = bflo(u.y), bx1 = bfhi(u.y);
        h.x = a0 * h.x + (1.0f - a0) * bx0;
        h.y = a1 * h.y + (1.0f - a1) * bx1;
        o[(size_t)t * NCH2] = h;
    }
}

extern "C" void kernel_launch(void* const* d_in, const int* in_sizes, int n_in,
                              void* d_out, int out_size, void* d_ws, size_t ws_size,
                              hipStream_t stream) {
    const float* x  = (const float*)d_in[0];
    const float* h0 = (const float*)d_in[1];
    const float* Wd = (const float*)d_in[2];
    const float* bd = (const float*)d_in[3];
    const float* Wb = (const float*)d_in[4];
    const float* bb = (const float*)d_in[5];
    float* out = (float*)d_out;

    // ws: only what scan_apply READS while out is being written:
    // db (64 MiB) + hstart (1 MiB) = 65 MiB.
    char* ws = (char*)d_ws;
    unsigned int* db = (unsigned int*)ws;                           // 64 MiB
    float* hstart = (float*)(ws + (size_t)M_DIM * H_DIM * 4);       // 1 MiB

    // d_out doubles as scratch until scan_apply overwrites it (64 MiB):
    //   xb 32 MiB | wdb 2 MiB | wbb 2 MiB | cA 1 MiB | cB 1 MiB   (= 38 MiB)
    char* ob = (char*)d_out;
    unsigned short* xb  = (unsigned short*)ob;
    unsigned short* wdb = (unsigned short*)(ob + ((size_t)32 << 20));
    unsigned short* wbb = (unsigned short*)(ob + ((size_t)34 << 20));
    float* cA = (float*)(ob + ((size_t)36 << 20));
    float* cB = (float*)(ob + ((size_t)37 << 20));

    convert_kernel<<<(XCELLS + 2 * WCELLS) / 256, 256, 0, stream>>>(x, Wd, Wb, xb, wdb, wbb);

    dim3 gProj(M_DIM / 128, H_DIM / 128);   // 128 x 8 = 1024 blocks of 512
    proj_kernel<<<gProj, 512, 0, stream>>>(xb, wdb, wbb, bd, bb, db);

    scan_reduce<<<dim3(NCHUNK, NCH2 / 256), 256, 0, stream>>>((const uint2*)db, (float2*)cA, (float2*)cB);
    scan_chunks<<<NCH2 / 256, 256, 0, stream>>>((const float2*)cA, (const float2*)cB, (const float2*)h0, (float2*)hstart);
    scan_apply<<<dim3(NCHUNK, NCH2 / 256), 256, 0, stream>>>((const uint2*)db, (const float2*)hstart, (float2*)out);
}

// Round 10
// 221.921 us; speedup vs baseline: 1.6738x; 1.0896x over previous
//
#include <hip/hip_runtime.h>
#include <hip/hip_bf16.h>

#define T_DIM 2048
#define B_DIM 8
#define D_DIM 1024
#define H_DIM 1024
#define M_DIM (T_DIM * B_DIM)   // 16384 rows
#define NCH (B_DIM * H_DIM)     // 8192 channels
#define CHUNK 64
#define NCHUNK (T_DIM / CHUNK)  // 32
#define NCH2 (NCH / 2)          // 4096 channel-pairs

typedef __bf16 bf16x8 __attribute__((ext_vector_type(8)));
typedef unsigned short us8 __attribute__((ext_vector_type(8)));
typedef float f32x4 __attribute__((ext_vector_type(4)));

__device__ __forceinline__ unsigned short f2bf(float f) {
    unsigned u = __float_as_uint(f);
    u += 0x7fffu + ((u >> 16) & 1u);   // round-to-nearest-even
    return (unsigned short)(u >> 16);
}
__device__ __forceinline__ float bflo(unsigned u) { return __uint_as_float(u << 16); }
__device__ __forceinline__ float bfhi(unsigned u) { return __uint_as_float(u & 0xffff0000u); }

// ---- one-shot fp32 -> bf16 conversion of x, W_delta, W_B ----
#define XCELLS  (M_DIM * D_DIM / 8)          // 2097152
#define WCELLS  (H_DIM * D_DIM / 8)          // 131072
__global__ __launch_bounds__(256) void convert_kernel(
    const float* __restrict__ x, const float* __restrict__ Wd,
    const float* __restrict__ Wb, unsigned short* __restrict__ xb,
    unsigned short* __restrict__ wdb, unsigned short* __restrict__ wbb)
{
    size_t cell = (size_t)blockIdx.x * 256 + threadIdx.x;
    const float* src; unsigned short* dst;
    if (cell < XCELLS)               { src = x  + cell * 8;                    dst = xb  + cell * 8; }
    else if (cell < XCELLS + WCELLS) { size_t c = cell - XCELLS;  src = Wd + c * 8; dst = wdb + c * 8; }
    else                             { size_t c = cell - XCELLS - WCELLS; src = Wb + c * 8; dst = wbb + c * 8; }
    float4 f0 = *(const float4*)src;
    float4 f1 = *(const float4*)(src + 4);
    us8 u;
    u[0]=f2bf(f0.x); u[1]=f2bf(f0.y); u[2]=f2bf(f0.z); u[3]=f2bf(f0.w);
    u[4]=f2bf(f1.x); u[5]=f2bf(f1.y); u[6]=f2bf(f1.z); u[7]=f2bf(f1.w);
    *(us8*)dst = u;
}

// ---- dual GEMM, 256Mx(128+128)N tile, 1024 threads (16 waves, 4Mx4N),
// each wave 64x32 per GEMM (acc 64 AGPR). 2-phase LDS double-buffer.
// LDS per buffer: A 2048 cells | B0 1024 | B1 1024 (16B cells, 64 KiB).
// Within-tile cell = row*8 + (kc ^ (row&7)): linear dest for global_load_lds,
// swizzle applied on the pre-swizzled GLOBAL source and on the ds_read slot.
__global__ __launch_bounds__(1024, 1) void proj_kernel(
    const unsigned short* __restrict__ xb, const unsigned short* __restrict__ wdb,
    const unsigned short* __restrict__ wbb, const float* __restrict__ bd,
    const float* __restrict__ bb, unsigned int* __restrict__ db)
{
    __shared__ us8 lds[2][4096];                 // 2 x 64 KiB

    const int tid  = threadIdx.x;
    const int lane = tid & 63;
    const int wid  = tid >> 6;                   // 0..15
    const int wm = wid >> 2, wn = wid & 3;       // 4x4 waves: 64 rows x 32 cols per GEMM
    const int bRow = blockIdx.x * 256;
    const int bCol = blockIdx.y * 128;

    f32x4 accD[4][2], accB[4][2];
    #pragma unroll
    for (int i = 0; i < 4; ++i)
        #pragma unroll
        for (int j = 0; j < 2; ++j) { accD[i][j] = (f32x4)0.0f; accB[i][j] = (f32x4)0.0f; }

    const unsigned short* aBase  = xb  + (size_t)bRow * D_DIM;
    const unsigned short* b0Base = wdb + (size_t)bCol * D_DIM;
    const unsigned short* b1Base = wbb + (size_t)bCol * D_DIM;

    auto stage = [&](int buf, int kt) {
        #pragma unroll
        for (int p = 0; p < 4; ++p) {            // p<2: A (2048 cells), p=2: B0, p=3: B1
            const unsigned short* base = (p < 2) ? aBase : (p == 2 ? b0Base : b1Base);
            int tileOff = (p < 2) ? 0 : (p == 2 ? 2048 : 3072);
            int woff = ((p < 2) ? p * 1024 : 0) + wid * 64;  // wave-uniform
            int w    = woff + lane;              // tile-local cell index
            int row  = w >> 3;
            int kc   = (w & 7) ^ (row & 7);      // pre-swizzled source slot
            __builtin_amdgcn_global_load_lds(
                (const __attribute__((address_space(1))) unsigned int*)
                    (base + (size_t)row * D_DIM + kt + kc * 8),
                (__attribute__((address_space(3))) unsigned int*)
                    (&lds[buf][tileOff + woff]),
                16, 0, 0);
        }
    };

    auto compute = [&](int buf) {
        #pragma unroll
        for (int ks = 0; ks < 2; ++ks) {
            const int kc = ks * 4 + (lane >> 4);
            const int sl = kc ^ (lane & 7);      // swizzled 16B slot
            bf16x8 aF[4], b0F[2], b1F[2];
            #pragma unroll
            for (int mt = 0; mt < 4; ++mt) {
                int r = wm * 64 + mt * 16 + (lane & 15);
                aF[mt] = __builtin_bit_cast(bf16x8, lds[buf][r * 8 + sl]);
            }
            #pragma unroll
            for (int nt = 0; nt < 2; ++nt) {
                int c = wn * 32 + nt * 16 + (lane & 15);
                b0F[nt] = __builtin_bit_cast(bf16x8, lds[buf][2048 + c * 8 + sl]);
                b1F[nt] = __builtin_bit_cast(bf16x8, lds[buf][3072 + c * 8 + sl]);
            }
            #pragma unroll
            for (int nt = 0; nt < 2; ++nt)
                #pragma unroll
                for (int mt = 0; mt < 4; ++mt) {
                    accD[mt][nt] = __builtin_amdgcn_mfma_f32_16x16x32_bf16(aF[mt], b0F[nt], accD[mt][nt], 0, 0, 0);
                    accB[mt][nt] = __builtin_amdgcn_mfma_f32_16x16x32_bf16(aF[mt], b1F[nt], accB[mt][nt], 0, 0, 0);
                }
        }
    };

    stage(0, 0);
    __syncthreads();
    for (int t = 0; t < 15; ++t) {
        stage((t + 1) & 1, (t + 1) * 64);        // prefetch next K-tile (other buffer)
        compute(t & 1);                          // MFMA on current buffer
        __syncthreads();                         // one barrier per K-step (drains vm+lgkm)
    }
    compute(1);

    // epilogue: decay = sigmoid(-(z+bd)) = exp(-softplus(z+bd)); bx = y+bb
    #pragma unroll
    for (int nt = 0; nt < 2; ++nt) {
        int c = bCol + wn * 32 + nt * 16 + (lane & 15);
        float bdv = bd[c], bbv = bb[c];
        #pragma unroll
        for (int mt = 0; mt < 4; ++mt) {
            int r0 = bRow + wm * 64 + mt * 16 + ((lane >> 4) << 2);
            #pragma unroll
            for (int reg = 0; reg < 4; ++reg) {
                float z  = accD[mt][nt][reg] + bdv;
                float dk = 1.0f / (1.0f + __expf(z));
                float bx = accB[mt][nt][reg] + bbv;
                db[(size_t)(r0 + reg) * H_DIM + c] =
                    (unsigned)f2bf(dk) | ((unsigned)f2bf(bx) << 16);
            }
        }
    }
}

// ---- chunked scan, uint2/float2 vectorized (2 channels/lane) ----
__global__ __launch_bounds__(256) void scan_reduce(
    const uint2* __restrict__ db2, float2* __restrict__ cA, float2* __restrict__ cB)
{
    int c2 = blockIdx.y * 256 + threadIdx.x;
    int i  = blockIdx.x;
    const uint2* p = db2 + (size_t)i * CHUNK * NCH2 + c2;
    float A0 = 1.0f, B0 = 0.0f, A1 = 1.0f, B1 = 0.0f;
    for (int t = 0; t < CHUNK; ++t) {
        uint2 u = p[(size_t)t * NCH2];
        float a0 = bflo(u.x), bx0 = bfhi(u.x);
        float a1 = bflo(u.y), bx1 = bfhi(u.y);
        A0 *= a0; B0 = a0 * B0 + (1.0f - a0) * bx0;
        A1 *= a1; B1 = a1 * B1 + (1.0f - a1) * bx1;
    }
    cA[i * NCH2 + c2] = make_float2(A0, A1);
    cB[i * NCH2 + c2] = make_float2(B0, B1);
}

// Each block recomputes its chunk-start state from the (L2-resident) chunk
// composites, then replays its chunk. scan_chunks kernel + hstart eliminated.
__global__ __launch_bounds__(256) void scan_apply(
    const uint2* __restrict__ db2, const float2* __restrict__ cA,
    const float2* __restrict__ cB, const float2* __restrict__ h0,
    float2* __restrict__ out2)
{
    int c2 = blockIdx.y * 256 + threadIdx.x;
    int i  = blockIdx.x;
    float2 h = h0[c2];
    for (int j = 0; j < i; ++j) {                // prefix over earlier chunks
        float2 a = cA[j * NCH2 + c2];
        float2 b = cB[j * NCH2 + c2];
        h.x = a.x * h.x + b.x;
        h.y = a.y * h.y + b.y;
    }
    const uint2* p = db2 + (size_t)i * CHUNK * NCH2 + c2;
    float2*      o = out2 + (size_t)i * CHUNK * NCH2 + c2;
    for (int t = 0; t < CHUNK; ++t) {
        uint2 u = p[(size_t)t * NCH2];
        float a0 = bflo(u.x), bx0 = bfhi(u.x);
        float a1 = bflo(u.y), bx1 = bfhi(u.y);
        h.x = a0 * h.x + (1.0f - a0) * bx0;
        h.y = a1 * h.y + (1.0f - a1) * bx1;
        o[(size_t)t * NCH2] = h;
    }
}

extern "C" void kernel_launch(void* const* d_in, const int* in_sizes, int n_in,
                              void* d_out, int out_size, void* d_ws, size_t ws_size,
                              hipStream_t stream) {
    const float* x  = (const float*)d_in[0];
    const float* h0 = (const float*)d_in[1];
    const float* Wd = (const float*)d_in[2];
    const float* bd = (const float*)d_in[3];
    const float* Wb = (const float*)d_in[4];
    const float* bb = (const float*)d_in[5];
    float* out = (float*)d_out;

    // ws: everything scan_apply READS while out is being written:
    // db (64 MiB) + cA (1 MiB) + cB (1 MiB) = 66 MiB (proven budget >= 71 MiB).
    char* ws = (char*)d_ws;
    unsigned int* db = (unsigned int*)ws;                           // 64 MiB
    float* cA = (float*)(ws + ((size_t)64 << 20));                  // 1 MiB
    float* cB = (float*)(ws + ((size_t)65 << 20));                  // 1 MiB

    // d_out doubles as scratch until scan_apply overwrites it:
    //   xb 32 MiB | wdb 2 MiB | wbb 2 MiB   (= 36 MiB of 64)
    char* ob = (char*)d_out;
    unsigned short* xb  = (unsigned short*)ob;
    unsigned short* wdb = (unsigned short*)(ob + ((size_t)32 << 20));
    unsigned short* wbb = (unsigned short*)(ob + ((size_t)34 << 20));

    convert_kernel<<<(XCELLS + 2 * WCELLS) / 256, 256, 0, stream>>>(x, Wd, Wb, xb, wdb, wbb);

    dim3 gProj(M_DIM / 256, H_DIM / 128);   // 64 x 8 = 512 blocks of 1024
    proj_kernel<<<gProj, 1024, 0, stream>>>(xb, wdb, wbb, bd, bb, db);

    scan_reduce<<<dim3(NCHUNK, NCH2 / 256), 256, 0, stream>>>((const uint2*)db, (float2*)cA, (float2*)cB);
    scan_apply<<<dim3(NCHUNK, NCH2 / 256), 256, 0, stream>>>(
        (const uint2*)db, (const float2*)cA, (const float2*)cB, (const float2*)h0, (float2*)out);
}